// Round 9
// baseline (104.473 us; speedup 1.0000x reference)
//
#include <hip/hip_runtime.h>
#include <hip/hip_bf16.h>
#include <float.h>
#include <math.h>

#define CDIM 128

typedef __attribute__((ext_vector_type(8))) short short8v;   // 8 bf16 = 1 MFMA A/B frag
typedef __attribute__((ext_vector_type(4))) float f32x4;     // MFMA C/D frag

__device__ __forceinline__ short bf16b(float f) {
    __hip_bfloat16 h = __float2bfloat16(f);
    return __builtin_bit_cast(short, h);
}

// fast tanh via hardware exp: tanh(y) = 1 - 2/(exp(2y)+1)
__device__ __forceinline__ float tanh_fast(float y) {
    float e = __expf(2.0f * y);
    return 1.0f - 2.0f / (e + 1.0f);
}

__device__ __forceinline__ int lower_bound_i(const int* __restrict__ b, int n, int v) {
    int lo = 0, hi = n;
    while (lo < hi) { int mid = (lo + hi) >> 1; if (b[mid] < v) lo = mid + 1; else hi = mid; }
    return lo;
}

__global__ void seg_bounds_kernel(const int* __restrict__ batch, int N, int G,
                                  int* __restrict__ seg) {
    int g = blockIdx.x * blockDim.x + threadIdx.x;
    if (g < G) seg[g] = lower_bound_i(batch, N, g);
    if (g == 0) seg[G] = N;
}

// Pre-pack proj_w into bf16 MFMA B-fragments.
// Frag f = ct*4+ks, lane l: col c = ct*16+(l&15), k = ks*32+(l>>4)*8+j  (j=0..7)
__global__ void wconv_kernel(const float* __restrict__ proj_w, short* __restrict__ wfrag) {
    int tid = blockIdx.x * 256 + threadIdx.x;       // 0..2047
    int f = tid >> 6, l = tid & 63;
    int c  = ((f >> 2) << 4) | (l & 15);
    int k0 = ((f & 3) << 5) | ((l >> 4) << 3);
    short8v v;
    #pragma unroll
    for (int j = 0; j < 8; ++j) v[j] = bf16b(proj_w[c * CDIM + k0 + j]);
    ((short8v*)wfrag)[tid] = v;
}

// Async DMA of 32 rows x 128 fp32 into LDS, 16B/lane, linear LDS dest.
// Swizzle lives in the GLOBAL source address (rule 21): LDS[row][f4] holds
// x_row[f4 ^ (row&7)], so reads use slot (f4' ^ (row&7)) — conflict-free
// 16B-granule XOR, and global stays 128B-line coalesced (XOR only flips
// low 3 bits of the f4 index).
__device__ __forceinline__ void dma_rows(const float* __restrict__ x, float* dst_base,
                                         int w, int lane, int row0, int rem) {
    #pragma unroll
    for (int j = 0; j < 4; ++j) {
        const int T = (w << 2) | j;               // 1KB transfer id (wave-uniform)
        const int row = (T << 1) | (lane >> 5);   // LDS row this lane fills
        const int f4 = lane & 31;                 // LDS 16B slot within row
        const size_t gr = (size_t)(row0 + min(row, rem - 1));   // clamp tail
        const float* src = x + (gr << 7) + ((f4 ^ (row & 7)) << 2);
        __builtin_amdgcn_global_load_lds(
            (__attribute__((address_space(1))) const void*)src,
            (__attribute__((address_space(3))) void*)(dst_base + (T << 8)),
            16, 0, 0);
    }
}

// One block (4 waves) per graph. Chunk = 32 rows, fp32 double-buffered LDS
// filled by global_load_lds (zero staging registers): chunk k+1's DMA issues
// at the top of body k and completes by the mid barrier (drain ~700cy after
// issue, hidden under MFMA+epilogue). Wave w owns col-tiles {2w,2w+1};
// pooling reads exact fp32 from LDS. 2 barriers/chunk. ~90 VGPR, 33KB LDS
// -> 4 blocks/CU.
__launch_bounds__(256, 4)
__global__ void pool_kernel(const float* __restrict__ x,
                            const short* __restrict__ wfrag,
                            const float* __restrict__ proj_b,
                            const float* __restrict__ score_w,
                            const float* __restrict__ score_b,
                            const int* __restrict__ seg,
                            float* __restrict__ out,
                            int N) {
    __shared__ __align__(16) float Xf[2][32 * 128];   // 2 x 16KB fp32, source-swizzled
    __shared__ float ps[32 * 4];                      // score partials [row][wave]

    const int g = blockIdx.x;
    const int t = threadIdx.x;
    const int lane = t & 63;
    const int w = t >> 6;                     // wave id: owns col-tiles 2w, 2w+1
    const int start = seg[g];
    const int cnt = seg[g + 1] - start;
    float4* og4 = (float4*)(out + (size_t)g * CDIM);

    if (cnt <= 0) {                           // empty graph pools to zeros
        if (t < 32) og4[t] = make_float4(0.f, 0.f, 0.f, 0.f);
        return;
    }

    // ---- prologue: DMA chunk 0 into buffer 0 (deepest latency first) ----
    dma_rows(x, Xf[0], w, lane, start, cnt);

    // W fragments for this wave's 2 column-tiles: 8 frags = 32 VGPR (L2-hot)
    short8v wf[2][4];
    {
        const short8v* wfg = (const short8v*)wfrag;
        #pragma unroll
        for (int j = 0; j < 2; ++j)
            #pragma unroll
            for (int ks = 0; ks < 4; ++ks)
                wf[j][ks] = wfg[((((w << 1) | j) << 2 | ks) << 6) | lane];
    }
    const int al = lane & 15, kq = lane >> 4;
    float swl[2], pbl[2];
    #pragma unroll
    for (int j = 0; j < 2; ++j) {
        swl[j] = score_w[(((w << 1) | j) << 4) + al];
        pbl[j] = proj_b[(((w << 1) | j) << 4) + al];
    }
    const float sb = score_b[0];

    const int rp = t >> 5;                    // pooling row phase (0..7)
    const int c4 = t & 31;                    // pooling f4 column slot

    float m_run = -FLT_MAX, l_run = 0.0f;
    float4 pa = make_float4(0.f, 0.f, 0.f, 0.f);

    const int nchunks = (cnt + 31) >> 5;
    __syncthreads();                          // chunk 0 in LDS (vmcnt drained)

    int bsel = 0;
    for (int c = 0; c < nchunks; ++c) {
        const float* A = Xf[bsel];
        const float4* Av = (const float4*)A;
        const int rem_c = min(32, cnt - (c << 5));

        // ---- issue chunk k+1 DMA into spare buffer (hidden under this body) ----
        if (c + 1 < nchunks)
            dma_rows(x, Xf[bsel ^ 1], w, lane, start + ((c + 1) << 5), cnt - ((c + 1) << 5));

        // ---- MFMA: 2 row-tiles x this wave's 2 col-tiles; A-frags from fp32 LDS ----
        #pragma unroll
        for (int rt = 0; rt < 2; ++rt) {
            const int arow = (rt << 4) | al;
            const int swz = arow & 7;
            f32x4 a0 = (f32x4){0.f, 0.f, 0.f, 0.f};
            f32x4 a1 = (f32x4){0.f, 0.f, 0.f, 0.f};
            #pragma unroll
            for (int ks = 0; ks < 4; ++ks) {
                const int fb = (ks << 3) | (kq << 1);
                float4 q0 = Av[(arow << 5) | (fb ^ swz)];
                float4 q1 = Av[(arow << 5) | ((fb + 1) ^ swz)];
                short8v af;
                af[0] = bf16b(q0.x); af[1] = bf16b(q0.y);
                af[2] = bf16b(q0.z); af[3] = bf16b(q0.w);
                af[4] = bf16b(q1.x); af[5] = bf16b(q1.y);
                af[6] = bf16b(q1.z); af[7] = bf16b(q1.w);
                a0 = __builtin_amdgcn_mfma_f32_16x16x32_bf16(af, wf[0][ks], a0, 0, 0, 0);
                a1 = __builtin_amdgcn_mfma_f32_16x16x32_bf16(af, wf[1][ks], a1, 0, 0, 0);
            }
            #pragma unroll
            for (int r = 0; r < 4; ++r) {     // C/D: channel=al, node = rt*16+kq*4+r
                float s = swl[0] * tanh_fast(a0[r] + pbl[0])
                        + swl[1] * tanh_fast(a1[r] + pbl[1]);
                s += __shfl_xor(s, 1); s += __shfl_xor(s, 2);
                s += __shfl_xor(s, 4); s += __shfl_xor(s, 8);
                if (al == 0) ps[(((rt << 4) | (kq << 2) | r) << 2) | w] = s;
            }
        }
        __syncthreads();                      // ps ready; chunk k+1 DMA drained

        // ---- all-wave softmax: lane L owns row L (L<32), shuffle-only ----
        float sv = -FLT_MAX;
        if (lane < rem_c) {
            float4 pp = *(const float4*)&ps[lane << 2];
            sv = pp.x + pp.y + pp.z + pp.w + sb;
        }
        float mx = sv;
        #pragma unroll
        for (int m = 1; m < 64; m <<= 1) mx = fmaxf(mx, __shfl_xor(mx, m));
        const float m_new = fmaxf(m_run, mx);
        float ev = (lane < rem_c) ? __expf(sv - m_new) : 0.f;
        float ssum = ev;
        #pragma unroll
        for (int m = 1; m < 64; m <<= 1) ssum += __shfl_xor(ssum, m);
        const float sc = __expf(m_run - m_new);       // first chunk: exp(-inf)=0
        m_run = m_new;
        l_run = l_run * sc + ssum;
        pa.x *= sc; pa.y *= sc; pa.z *= sc; pa.w *= sc;

        // ---- pooling accumulate: exact fp32 from LDS, e via shfl ----
        #pragma unroll
        for (int i = 0; i < 4; ++i) {
            const int row = rp | (i << 3);
            const float em = __shfl(ev, row);         // 0 for pad rows
            float4 xv = Av[(row << 5) | (c4 ^ (row & 7))];
            pa.x += em * xv.x; pa.y += em * xv.y;
            pa.z += em * xv.z; pa.w += em * xv.w;
        }
        __syncthreads();                      // A reads done -> next DMA may overwrite
        bsel ^= 1;
    }

    // ---- cross-phase reduce (alias onto Xf[0]) + normalize + store ----
    *(float4*)&Xf[0][t << 2] = pa;            // slot t = rp*32 + c4
    __syncthreads();
    if (t < 32) {
        float4 v = make_float4(0.f, 0.f, 0.f, 0.f);
        #pragma unroll
        for (int j = 0; j < 8; ++j) {
            float4 r = *(const float4*)&Xf[0][((j << 5) | t) << 2];
            v.x += r.x; v.y += r.y; v.z += r.z; v.w += r.w;
        }
        const float inv = 1.0f / fmaxf(l_run, 1e-30f);
        v.x *= inv; v.y *= inv; v.z *= inv; v.w *= inv;
        og4[t] = v;
    }
}

extern "C" void kernel_launch(void* const* d_in, const int* in_sizes, int n_in,
                              void* d_out, int out_size, void* d_ws, size_t ws_size,
                              hipStream_t stream) {
    const float* x       = (const float*)d_in[0];
    const float* proj_w  = (const float*)d_in[1];
    const float* proj_b  = (const float*)d_in[2];
    const float* score_w = (const float*)d_in[3];
    const float* score_b = (const float*)d_in[4];
    const int*   batch   = (const int*)d_in[5];

    const int N = in_sizes[0] / CDIM;
    const int G = out_size / CDIM;

    int*   seg   = (int*)d_ws;
    short* wfrag = (short*)((char*)d_ws + (((size_t)(G + 1) * 4 + 255) & ~(size_t)255));

    seg_bounds_kernel<<<(G + 255) / 256, 256, 0, stream>>>(batch, N, G, seg);
    wconv_kernel<<<8, 256, 0, stream>>>(proj_w, wfrag);
    pool_kernel<<<G, 256, 0, stream>>>(x, wfrag, proj_b, score_w, score_b,
                                       seg, (float*)d_out, N);
}

// Round 10
// 96.722 us; speedup vs baseline: 1.0801x; 1.0801x over previous
//
#include <hip/hip_runtime.h>
#include <hip/hip_bf16.h>
#include <float.h>
#include <math.h>

#define CDIM 128

typedef __attribute__((ext_vector_type(8))) short short8v;   // 8 bf16 = 1 MFMA A/B frag
typedef __attribute__((ext_vector_type(4))) short short4v;   // 4 bf16 (8B LDS store)
typedef __attribute__((ext_vector_type(4))) float f32x4;     // MFMA C/D frag

__device__ __forceinline__ short bf16b(float f) {
    __hip_bfloat16 h = __float2bfloat16(f);
    return __builtin_bit_cast(short, h);
}

// fast tanh via hardware exp: tanh(y) = 1 - 2/(exp(2y)+1)
__device__ __forceinline__ float tanh_fast(float y) {
    float e = __expf(2.0f * y);
    return 1.0f - 2.0f / (e + 1.0f);
}

__device__ __forceinline__ int lower_bound_i(const int* __restrict__ b, int n, int v) {
    int lo = 0, hi = n;
    while (lo < hi) { int mid = (lo + hi) >> 1; if (b[mid] < v) lo = mid + 1; else hi = mid; }
    return lo;
}

__global__ void seg_bounds_kernel(const int* __restrict__ batch, int N, int G,
                                  int* __restrict__ seg) {
    int g = blockIdx.x * blockDim.x + threadIdx.x;
    if (g < G) seg[g] = lower_bound_i(batch, N, g);
    if (g == 0) seg[G] = N;
}

// Pre-pack proj_w into bf16 MFMA fragments (A/B layout coincide for 16x16x32).
// Frag f = ct*4+ks, lane l: chan c = ct*16+(l&15), k = ks*32+(l>>4)*8+j (j=0..7)
__global__ void wconv_kernel(const float* __restrict__ proj_w, short* __restrict__ wfrag) {
    int tid = blockIdx.x * 256 + threadIdx.x;       // 0..2047
    int f = tid >> 6, l = tid & 63;
    int c  = ((f >> 2) << 4) | (l & 15);
    int k0 = ((f & 3) << 5) | ((l >> 4) << 3);
    short8v v;
    #pragma unroll
    for (int j = 0; j < 8; ++j) v[j] = bf16b(proj_w[c * CDIM + k0 + j]);
    ((short8v*)wfrag)[tid] = v;
}

// One block (4 waves) per graph — R4 skeleton with SWAPPED MFMA operands:
//   acc = mfma(W_frag, X_frag): D[m=channel][n=row] -> col(lane&15)=row.
//   Each lane holds 8 channels of ONE row => score dot is in-lane VALU,
//   epilogue needs ZERO shuffles (was 64/wave/chunk): one unconditional
//   ds_write_b32 of the per-(row, w, kq) partial into padded ps[].
//   wave0 sums 16 partials/row and does the only shuffle softmax (12 ops).
//   LDS-pipe load per chunk drops ~2.6x vs R4 (the per-CU DS pipe was the
//   hidden binder: shuffles are ds_bpermute).
// fp32 x stays in registers for exact pooling; bf16-once swizzled XsB feeds
// conflict-free ds_read_b128 B-frags. 3 barriers/chunk.
__launch_bounds__(256, 4)
__global__ void pool_kernel(const float* __restrict__ x,
                            const short* __restrict__ wfrag,
                            const float* __restrict__ proj_b,
                            const float* __restrict__ score_w,
                            const float* __restrict__ score_b,
                            const int* __restrict__ seg,
                            float* __restrict__ out,
                            int N) {
    // LDS: 16KB XsB + 5.1KB ps + cs/bc ≈ 21.4KB -> 4 blocks/CU
    __shared__ __align__(16) short XsB[64 * 128]; // bf16: row*128 + (k ^ ((row&7)<<3))
    __shared__ float ps[64 * 20];                 // partials [row][w*4+kq], stride 20
    __shared__ float cs[64];                      // exp weights
    __shared__ float bc[2];                       // {scale, chunk exp-sum}

    const int g = blockIdx.x;
    const int t = threadIdx.x;
    const int lane = t & 63;
    const int w = t >> 6;                     // wave id: owns col-tiles 2w, 2w+1
    const int start = seg[g];
    const int cnt = seg[g + 1] - start;
    float4* og4 = (float4*)(out + (size_t)g * CDIM);

    if (cnt <= 0) {                           // empty graph pools to zeros
        if (t < 32) og4[t] = make_float4(0.f, 0.f, 0.f, 0.f);
        return;
    }

    // W fragments for this wave's 2 channel-tiles: 8 frags = 32 VGPR
    short8v wf[2][4];
    {
        const short8v* wfg = (const short8v*)wfrag;
        #pragma unroll
        for (int j = 0; j < 2; ++j)
            #pragma unroll
            for (int ks = 0; ks < 4; ++ks)
                wf[j][ks] = wfg[((((w << 1) | j) << 2 | ks) << 6) | lane];
    }
    const int al = lane & 15, kq = lane >> 4;
    // per-lane score/bias slices: chans (2w+j)*16 + kq*4 + r
    float4 swl4[2], pbl4[2];
    #pragma unroll
    for (int j = 0; j < 2; ++j) {
        swl4[j] = *(const float4*)&score_w[((((w << 1) | j) << 4) | (kq << 2))];
        pbl4[j] = *(const float4*)&proj_b[((((w << 1) | j) << 4) | (kq << 2))];
    }
    const float sb = score_b[0];

    const float4* __restrict__ x4 = (const float4*)x;
    const int g8 = t >> 5;                    // stage/pool row phase (0..7)
    const int c4 = t & 31;                    // float4 column slot

    float m_run = -FLT_MAX, l_run = 0.0f;
    float4 pa = make_float4(0.f, 0.f, 0.f, 0.f);

    for (int cb = 0; cb < cnt; cb += 64) {
        const int rem = cnt - cb;             // >=1; rows >= rem are padding

        // ---- stage: global -> fp32 regs + bf16 swizzled LDS (converted ONCE) ----
        float4 xr[8];
        #pragma unroll
        for (int i = 0; i < 8; ++i) {
            int row = g8 + (i << 3);
            size_t gr = (size_t)min(start + cb + row, N - 1);   // clamp (pads masked)
            xr[i] = x4[gr * 32 + c4];
        }
        #pragma unroll
        for (int i = 0; i < 8; ++i) {
            int row = g8 + (i << 3);
            short4v b;
            b[0] = bf16b(xr[i].x); b[1] = bf16b(xr[i].y);
            b[2] = bf16b(xr[i].z); b[3] = bf16b(xr[i].w);
            *(short4v*)&XsB[(row << 7) | ((c4 << 2) ^ ((row & 7) << 3))] = b;
        }
        __syncthreads();                      // sync1: XsB ready (prev readers done)

        // ---- per row-tile: 8 MFMA (swapped) + in-lane tanh/score, 0 shuffles ----
        #pragma unroll
        for (int rt = 0; rt < 4; ++rt) {
            const int arow = (rt << 4) | al;
            const int rsw = (arow & 7) << 3;
            short8v xf[4];
            #pragma unroll
            for (int ks = 0; ks < 4; ++ks)
                xf[ks] = *(const short8v*)&XsB[(arow << 7) | (((ks << 5) | (kq << 3)) ^ rsw)];
            f32x4 a0 = (f32x4){0.f, 0.f, 0.f, 0.f};
            f32x4 a1 = (f32x4){0.f, 0.f, 0.f, 0.f};
            #pragma unroll
            for (int ks = 0; ks < 4; ++ks) {
                a0 = __builtin_amdgcn_mfma_f32_16x16x32_bf16(wf[0][ks], xf[ks], a0, 0, 0, 0);
                a1 = __builtin_amdgcn_mfma_f32_16x16x32_bf16(wf[1][ks], xf[ks], a1, 0, 0, 0);
            }
            // D[m=chan=(2w+j)*16+kq*4+r][n=row=rt*16+al]: in-lane dot over 8 chans
            float scp = 0.f;
            #pragma unroll
            for (int r = 0; r < 4; ++r) {
                scp += swl4[0][r] * tanh_fast(a0[r] + pbl4[0][r]);
                scp += swl4[1][r] * tanh_fast(a1[r] + pbl4[1][r]);
            }
            ps[((rt << 4) | al) * 20 + ((w << 2) | kq)] = scp;
        }
        __syncthreads();                      // sync2: ps complete, XsB reads done

        // ---- wave0 softmax: sum 16 partials per row + 12 shuffles ----
        if (t < 64) {
            float sv = -FLT_MAX;
            if (t < rem) {
                const float* p = &ps[t * 20];
                float4 q0 = *(const float4*)&p[0],  q1 = *(const float4*)&p[4];
                float4 q2 = *(const float4*)&p[8],  q3 = *(const float4*)&p[12];
                sv = ((q0.x + q0.y) + (q0.z + q0.w)) + ((q1.x + q1.y) + (q1.z + q1.w))
                   + ((q2.x + q2.y) + (q2.z + q2.w)) + ((q3.x + q3.y) + (q3.z + q3.w)) + sb;
            }
            float mx = sv;
            #pragma unroll
            for (int m = 1; m < 64; m <<= 1) mx = fmaxf(mx, __shfl_xor(mx, m));
            const float m_new = fmaxf(m_run, mx);
            float e = (t < rem) ? __expf(sv - m_new) : 0.f;
            float ssum = e;
            #pragma unroll
            for (int m = 1; m < 64; m <<= 1) ssum += __shfl_xor(ssum, m);
            cs[t] = e;
            if (t == 0) { bc[0] = __expf(m_run - m_new); bc[1] = ssum; }
            m_run = m_new;                    // wave0-private running max
        }
        __syncthreads();                      // sync3: cs/bc ready

        // ---- rescale + pooling accumulate (registers + cs broadcast) ----
        const float sc = bc[0];
        l_run = l_run * sc + bc[1];
        pa.x *= sc; pa.y *= sc; pa.z *= sc; pa.w *= sc;
        #pragma unroll
        for (int i = 0; i < 8; ++i) {
            float em = cs[g8 + (i << 3)];             // 0 for pad rows; 2-addr broadcast
            pa.x += em * xr[i].x; pa.y += em * xr[i].y;
            pa.z += em * xr[i].z; pa.w += em * xr[i].w;
        }
    }

    // ---- cross-phase reduce (alias red onto XsB) + normalize + store ----
    float* red = (float*)XsB;                 // safe: XsB reads ended at last sync2
    *(float4*)&red[(g8 << 7) + (c4 << 2)] = pa;
    __syncthreads();
    if (t < 32) {
        float4 v = make_float4(0.f, 0.f, 0.f, 0.f);
        #pragma unroll
        for (int j = 0; j < 8; ++j) {
            float4 r = *(const float4*)&red[(j << 7) + (t << 2)];
            v.x += r.x; v.y += r.y; v.z += r.z; v.w += r.w;
        }
        const float inv = 1.0f / fmaxf(l_run, 1e-30f);
        v.x *= inv; v.y *= inv; v.z *= inv; v.w *= inv;
        og4[t] = v;
    }
}

extern "C" void kernel_launch(void* const* d_in, const int* in_sizes, int n_in,
                              void* d_out, int out_size, void* d_ws, size_t ws_size,
                              hipStream_t stream) {
    const float* x       = (const float*)d_in[0];
    const float* proj_w  = (const float*)d_in[1];
    const float* proj_b  = (const float*)d_in[2];
    const float* score_w = (const float*)d_in[3];
    const float* score_b = (const float*)d_in[4];
    const int*   batch   = (const int*)d_in[5];

    const int N = in_sizes[0] / CDIM;
    const int G = out_size / CDIM;

    int*   seg   = (int*)d_ws;
    short* wfrag = (short*)((char*)d_ws + (((size_t)(G + 1) * 4 + 255) & ~(size_t)255));

    seg_bounds_kernel<<<(G + 255) / 256, 256, 0, stream>>>(batch, N, G, seg);
    wconv_kernel<<<8, 256, 0, stream>>>(proj_w, wfrag);
    pool_kernel<<<G, 256, 0, stream>>>(x, wfrag, proj_b, score_w, score_b,
                                       seg, (float*)d_out, N);
}